// Round 1
// baseline (1021.563 us; speedup 1.0000x reference)
//
#include <hip/hip_runtime.h>

#define D_INF 64
#define DEF 16   // edge feature dim
#define HF 16    // hidden dim

// ---------------- CSR build ----------------

__global__ __launch_bounds__(256) void k_hist(const int* __restrict__ dst, int E, int* __restrict__ deg) {
    int i = blockIdx.x * blockDim.x + threadIdx.x;
    if (i < E) atomicAdd(&deg[dst[i]], 1);
}

#define SCAN_B 256
__global__ __launch_bounds__(SCAN_B) void k_scan_partial(const int* __restrict__ deg, int N, int* __restrict__ partial) {
    __shared__ int s[SCAN_B];
    int i = blockIdx.x * SCAN_B + threadIdx.x;
    s[threadIdx.x] = (i < N) ? deg[i] : 0;
    __syncthreads();
    for (int off = SCAN_B / 2; off > 0; off >>= 1) {
        if (threadIdx.x < off) s[threadIdx.x] += s[threadIdx.x + off];
        __syncthreads();
    }
    if (threadIdx.x == 0) partial[blockIdx.x] = s[0];
}

__global__ __launch_bounds__(1024) void k_scan_top(int* __restrict__ partial, int P) {
    __shared__ int s[1024];
    int t = threadIdx.x;
    int orig = (t < P) ? partial[t] : 0;
    s[t] = orig;
    __syncthreads();
    for (int o = 1; o < 1024; o <<= 1) {
        int v = (t >= o) ? s[t - o] : 0;
        __syncthreads();
        s[t] += v;
        __syncthreads();
    }
    if (t < P) partial[t] = s[t] - orig;   // exclusive prefix of chunk sums
}

__global__ __launch_bounds__(SCAN_B) void k_scan_final(const int* __restrict__ deg, const int* __restrict__ partial,
                                                       int N, int* __restrict__ row_ptr, int* __restrict__ cursor) {
    __shared__ int s[SCAN_B];
    int t = threadIdx.x;
    int i = blockIdx.x * SCAN_B + t;
    int d = (i < N) ? deg[i] : 0;
    s[t] = d;
    __syncthreads();
    for (int o = 1; o < SCAN_B; o <<= 1) {
        int v = (t >= o) ? s[t - o] : 0;
        __syncthreads();
        s[t] += v;
        __syncthreads();
    }
    int excl = s[t] - d + partial[blockIdx.x];
    if (i < N) {
        row_ptr[i] = excl;
        cursor[i] = excl;
        if (i == N - 1) row_ptr[N] = excl + d;
    }
}

__global__ __launch_bounds__(256) void k_scatter(const int* __restrict__ src, const int* __restrict__ dst, int E,
                                                 int* __restrict__ cursor, int* __restrict__ csr_src, int* __restrict__ csr_eid) {
    int e = blockIdx.x * blockDim.x + threadIdx.x;
    if (e < E) {
        int d = dst[e];
        int pos = atomicAdd(&cursor[d], 1);
        csr_src[pos] = src[e];
        csr_eid[pos] = e;
    }
}

// ---------------- node transform: xt1 = x @ Wm1[0:64,:] ----------------
__global__ __launch_bounds__(256) void k_xt1(const float* __restrict__ x, const float* __restrict__ Wm1,
                                             int N, float* __restrict__ xt1) {
    int t = blockIdx.x * blockDim.x + threadIdx.x;
    int n = t >> 4, f = t & 15;
    if (n >= N) return;
    const float4* xr4 = (const float4*)(x + (size_t)n * D_INF);
    float acc = 0.f;
#pragma unroll
    for (int k4 = 0; k4 < 16; k4++) {
        float4 v = xr4[k4];
        int k = 4 * k4;
        acc += v.x * Wm1[(k + 0) * HF + f];
        acc += v.y * Wm1[(k + 1) * HF + f];
        acc += v.z * Wm1[(k + 2) * HF + f];
        acc += v.w * Wm1[(k + 3) * HF + f];
    }
    xt1[(size_t)n * HF + f] = acc;
}

// ---------------- conv1 aggregate + node update ----------------
// wave per node; 64 lanes = 4 edges x 16 features
__global__ __launch_bounds__(256) void k_conv1(const float* __restrict__ xt1, const float* __restrict__ eattr,
                                               const int* __restrict__ csr_src, const int* __restrict__ csr_eid,
                                               const int* __restrict__ row_ptr, const float* __restrict__ x,
                                               const float* __restrict__ Wm1, const float* __restrict__ b1,
                                               const float* __restrict__ Ws1, const float* __restrict__ bs1,
                                               int N, float* __restrict__ h1, float* __restrict__ agge) {
    int lane = threadIdx.x & 63;
    int w = threadIdx.x >> 6;                     // wave in block (0..3)
    int node = (int)((blockIdx.x * blockDim.x + threadIdx.x) >> 6);
    int sub = lane >> 4, f = lane & 15;
    __shared__ float xs[4][D_INF];
    __shared__ float es[4][HF];

    bool valid = node < N;
    int r0 = 0, r1 = 0;
    if (valid) { r0 = row_ptr[node]; r1 = row_ptr[node + 1]; }

    float acc_m = 0.f, acc_e = 0.f;
    for (int j = r0 + sub; j < r1; j += 4) {
        int s = csr_src[j];
        int eid = csr_eid[j];
        acc_m += xt1[(size_t)s * HF + f];
        acc_e += eattr[(size_t)eid * DEF + f];
    }
    acc_m += __shfl_xor(acc_m, 16);
    acc_m += __shfl_xor(acc_m, 32);
    acc_e += __shfl_xor(acc_e, 16);
    acc_e += __shfl_xor(acc_e, 32);

    float xl = valid ? x[(size_t)node * D_INF + lane] : 0.f;
    xs[w][lane] = xl;
    if (lane < 16) es[w][lane] = acc_e;
    __syncthreads();

    if (valid && lane < 16) {
        float degf = (float)(r1 - r0);
        float v = acc_m + degf * b1[f] + bs1[f];
#pragma unroll
        for (int k = 0; k < D_INF; k++) v += xs[w][k] * Ws1[k * HF + f];
#pragma unroll
        for (int k = 0; k < DEF; k++) v += es[w][k] * Wm1[(D_INF + k) * HF + f];
        h1[(size_t)node * HF + f] = fmaxf(v, 0.f);
        agge[(size_t)node * HF + f] = acc_e;
    }
}

// ---------------- node transforms for conv2 ----------------
// xt2 = h1 @ Wm2[0:16,:];  h2base = h1@Ws2 + bs2 + agge@Wm2[16:32,:] + deg*b2
__global__ __launch_bounds__(256) void k_node2(const float* __restrict__ h1, const float* __restrict__ agge,
                                               const int* __restrict__ deg,
                                               const float* __restrict__ Wm2, const float* __restrict__ b2,
                                               const float* __restrict__ Ws2, const float* __restrict__ bs2,
                                               int N, float* __restrict__ xt2, float* __restrict__ h2base) {
    int t = blockIdx.x * blockDim.x + threadIdx.x;
    int n = t >> 4, f = t & 15;
    if (n >= N) return;
    float degf = (float)deg[n];
    float xv = 0.f;
    float hb = bs2[f] + degf * b2[f];
#pragma unroll
    for (int k = 0; k < HF; k++) {
        float hk = h1[(size_t)n * HF + k];
        xv += hk * Wm2[k * HF + f];
        hb += hk * Ws2[k * HF + f];
    }
#pragma unroll
    for (int k = 0; k < DEF; k++) {
        hb += agge[(size_t)n * HF + k] * Wm2[(HF + k) * HF + f];
    }
    xt2[(size_t)n * HF + f] = xv;
    h2base[(size_t)n * HF + f] = hb;
}

// ---------------- conv2 aggregate + final projection ----------------
__global__ __launch_bounds__(256) void k_conv2(const float* __restrict__ xt2, const int* __restrict__ csr_src,
                                               const int* __restrict__ row_ptr, const float* __restrict__ h2base,
                                               const float* __restrict__ W3, const float* __restrict__ b3,
                                               int N, float* __restrict__ out) {
    int lane = threadIdx.x & 63;
    int node = (int)((blockIdx.x * blockDim.x + threadIdx.x) >> 6);
    if (node >= N) return;                       // no LDS/barrier in this kernel
    int sub = lane >> 4, f = lane & 15;
    int r0 = row_ptr[node], r1 = row_ptr[node + 1];
    float acc = 0.f;
    for (int j = r0 + sub; j < r1; j += 4) acc += xt2[(size_t)csr_src[j] * HF + f];
    acc += __shfl_xor(acc, 16);
    acc += __shfl_xor(acc, 32);
    float h2 = h2base[(size_t)node * HF + f] + acc;
    float o = b3[lane];
#pragma unroll
    for (int k = 0; k < HF; k++) {
        float hk = __shfl(h2, k, 64);            // lane k holds feature k
        o += hk * W3[k * D_INF + lane];
    }
    out[(size_t)node * D_INF + lane] = o;
}

// ---------------- launch ----------------

static inline size_t align256(size_t x) { return (x + 255) & ~(size_t)255; }

extern "C" void kernel_launch(void* const* d_in, const int* in_sizes, int n_in,
                              void* d_out, int out_size, void* d_ws, size_t ws_size,
                              hipStream_t stream) {
    const float* x    = (const float*)d_in[0];
    const int*   ei   = (const int*)d_in[1];
    const float* eatt = (const float*)d_in[2];
    const float* Wm1  = (const float*)d_in[3];
    const float* b1   = (const float*)d_in[4];
    const float* Ws1  = (const float*)d_in[5];
    const float* bs1  = (const float*)d_in[6];
    const float* Wm2  = (const float*)d_in[7];
    const float* b2   = (const float*)d_in[8];
    const float* Ws2  = (const float*)d_in[9];
    const float* bs2  = (const float*)d_in[10];
    const float* W3   = (const float*)d_in[11];
    const float* b3   = (const float*)d_in[12];
    float* out = (float*)d_out;

    int N = in_sizes[0] / D_INF;
    int E = in_sizes[1] / 2;
    const int* src = ei;
    const int* dst = ei + E;

    char* ws = (char*)d_ws;
    size_t off = 0;
    auto alloc = [&](size_t bytes) -> void* { void* p = ws + off; off = align256(off + bytes); return p; };

    int*   deg     = (int*)alloc((size_t)N * 4);
    int*   row_ptr = (int*)alloc((size_t)(N + 1) * 4);
    int*   cursor  = (int*)alloc((size_t)N * 4);
    int*   partial = (int*)alloc(1024 * 4);
    int*   csr_src = (int*)alloc((size_t)E * 4);
    int*   csr_eid = (int*)alloc((size_t)E * 4);
    float* xt1     = (float*)alloc((size_t)N * HF * 4);
    float* h1      = (float*)alloc((size_t)N * HF * 4);
    float* agge    = (float*)alloc((size_t)N * HF * 4);
    float* xt2     = (float*)alloc((size_t)N * HF * 4);
    float* h2base  = (float*)alloc((size_t)N * HF * 4);
    (void)ws_size; (void)n_in; (void)out_size;

    int P = (N + SCAN_B - 1) / SCAN_B;   // 391 for N=100k; k_scan_top handles P<=1024

    hipMemsetAsync(deg, 0, (size_t)N * 4, stream);

    dim3 blk(256);
    k_hist<<<dim3((E + 255) / 256), blk, 0, stream>>>(dst, E, deg);
    k_scan_partial<<<dim3(P), dim3(SCAN_B), 0, stream>>>(deg, N, partial);
    k_scan_top<<<dim3(1), dim3(1024), 0, stream>>>(partial, P);
    k_scan_final<<<dim3(P), dim3(SCAN_B), 0, stream>>>(deg, partial, N, row_ptr, cursor);
    k_scatter<<<dim3((E + 255) / 256), blk, 0, stream>>>(src, dst, E, cursor, csr_src, csr_eid);

    k_xt1<<<dim3((N * HF + 255) / 256), blk, 0, stream>>>(x, Wm1, N, xt1);
    k_conv1<<<dim3((N + 3) / 4), blk, 0, stream>>>(xt1, eatt, csr_src, csr_eid, row_ptr, x,
                                                   Wm1, b1, Ws1, bs1, N, h1, agge);
    k_node2<<<dim3((N * HF + 255) / 256), blk, 0, stream>>>(h1, agge, deg, Wm2, b2, Ws2, bs2,
                                                            N, xt2, h2base);
    k_conv2<<<dim3((N + 3) / 4), blk, 0, stream>>>(xt2, csr_src, row_ptr, h2base, W3, b3, N, out);
}